// Round 1
// baseline (262.033 us; speedup 1.0000x reference)
//
#include <hip/hip_runtime.h>
#include <hip/hip_bf16.h>
#include <stdint.h>

// Problem: B=32, C_IN=128, H=W=64, K=8, C_OUT=128, KS=3, HID=512, pad=1
// Pipeline:
//  1) pool_convert: x fp32 NCHW -> pooled means (atomics) + xT bf16 NHWC
//  2) attn_mlp:     pooled -> MLP -> scores -> softmax alphas + agg_b
//  3) agg_weights:  alphas x kernels_weights -> aggw bf16 [b][tap][co][ci]
//  4) dyn_conv:     implicit-GEMM conv, 16x16x32 bf16 MFMA, 128x128 tiles

typedef __bf16 v8bf __attribute__((ext_vector_type(8)));
typedef float  v4f  __attribute__((ext_vector_type(4)));

// ---- workspace layout (bytes) ----
#define XT_OFF     0u
#define XT_BYTES   (32u*4096u*128u*2u)        // 33,554,432  x as bf16 NHWC
#define AGGW_OFF   (XT_OFF + XT_BYTES)
#define AGGW_BYTES (32u*9u*128u*128u*2u)      // 9,437,184   [b][tap][co][ci]
#define POOL_OFF   (AGGW_OFF + AGGW_BYTES)
#define POOL_BYTES (32u*128u*4u)
#define ALPHA_OFF  (POOL_OFF + POOL_BYTES)
#define ALPHA_BYTES (32u*8u*4u)
#define AGGB_OFF   (ALPHA_OFF + ALPHA_BYTES)
#define AGGB_BYTES (32u*128u*4u)

typedef const void __attribute__((address_space(1))) gconst_t;
typedef void       __attribute__((address_space(3))) ldsv_t;

__device__ __forceinline__ void g2l16(const void* g, void* l) {
  // async global->LDS, 16B/lane; LDS dest must be wave-uniform base (HW adds lane*16)
  __builtin_amdgcn_global_load_lds((gconst_t*)g, (ldsv_t*)l, 16, 0, 0);
}

// ---------------- Kernel 1: pooling + NCHW->NHWC bf16 convert ----------------
// grid = B*H = 2048 blocks, 256 threads. Each block handles one (b,h) row slab.
__global__ __launch_bounds__(256) void pool_convert_kernel(
    const float* __restrict__ x, float* __restrict__ pooled,
    __hip_bfloat16* __restrict__ xT) {
  const int b = blockIdx.x >> 6;
  const int h = blockIdx.x & 63;
  const int tid = threadIdx.x;
  const int wv = tid >> 6, lane = tid & 63;
  // [w][c] transpose buffer; pitch 130 elems (260B) => 2-way bank aliasing (free)
  __shared__ __align__(16) __hip_bfloat16 sT[64 * 130];

  const float* xrow = x + (((size_t)b * 128) << 12) + (h << 6);
  for (int i = 0; i < 32; ++i) {
    int c = wv * 32 + i;                       // each wave: 32 channels
    float v = xrow[((size_t)c << 12) + lane];  // coalesced 256B per wave
    sT[lane * 130 + c] = __float2bfloat16(v);
    float s = v;
    #pragma unroll
    for (int m = 32; m > 0; m >>= 1) s += __shfl_xor(s, m);
    if (lane == 0) atomicAdd(pooled + b * 128 + c, s * (1.0f / 4096.0f));
  }
  __syncthreads();
  // write NHWC: position (h,pw) has 256B of ci; 4 threads/position, 64B each
  const int pw = tid >> 2;
  const int piece = tid & 3;
  const uint32_t* s32 = (const uint32_t*)sT;
  uint32_t vals[16];
  #pragma unroll
  for (int j = 0; j < 16; ++j) vals[j] = s32[pw * 65 + piece * 16 + j];
  char* dst = (char*)xT + ((((size_t)b << 6) + h) * 64 + pw) * 256 + piece * 64;
  #pragma unroll
  for (int j = 0; j < 4; ++j)
    ((uint4*)dst)[j] = make_uint4(vals[4*j], vals[4*j+1], vals[4*j+2], vals[4*j+3]);
}

// ---------------- Kernel 2: MLP + prompt scores + softmax + agg_b ------------
// grid = 32 (one block per sample), 256 threads, all fp32.
__global__ __launch_bounds__(256) void attn_mlp_kernel(
    const float* __restrict__ pooled, const float* __restrict__ w1,
    const float* __restrict__ b1, const float* __restrict__ w2,
    const float* __restrict__ b2, const float* __restrict__ prompt,
    const float* __restrict__ kbias, float* __restrict__ alphas,
    float* __restrict__ aggb) {
  const int b = blockIdx.x;
  const int tid = threadIdx.x;
  __shared__ float sP[128], sH[512], sS[512], sSc[8], sA[8];

  if (tid < 128) sP[tid] = pooled[b * 128 + tid];
  __syncthreads();

  for (int j = tid; j < 512; j += 256) {           // h = relu(pooled @ w1^T + b1)
    float acc = b1[j];
    const float* wr = w1 + j * 128;
    #pragma unroll 8
    for (int i = 0; i < 128; ++i) acc = fmaf(wr[i], sP[i], acc);
    sH[j] = fmaxf(acc, 0.0f);
  }
  __syncthreads();

  for (int j = tid; j < 512; j += 256) {           // s = h @ w2^T + b2
    float acc = b2[j];
    const float* wr = w2 + j * 512;
    #pragma unroll 8
    for (int i = 0; i < 512; ++i) acc = fmaf(wr[i], sH[i], acc);
    sS[j] = acc;
  }
  __syncthreads();

  const int wv = tid >> 6, lane = tid & 63;
  for (int k = wv; k < 8; k += 4) {                // scores[k] = <s, prompt[k]>
    float p = 0.0f;
    const float* pr = prompt + k * 512;
    #pragma unroll
    for (int i = lane; i < 512; i += 64) p = fmaf(pr[i], sS[i], p);
    #pragma unroll
    for (int m = 32; m > 0; m >>= 1) p += __shfl_xor(p, m);
    if (lane == 0) sSc[k] = p;
  }
  __syncthreads();

  if (tid == 0) {                                   // softmax over 8 kernels
    float mx = sSc[0];
    for (int k = 1; k < 8; ++k) mx = fmaxf(mx, sSc[k]);
    float sum = 0.0f, e[8];
    for (int k = 0; k < 8; ++k) { e[k] = expf(sSc[k] - mx); sum += e[k]; }
    float inv = 1.0f / sum;
    for (int k = 0; k < 8; ++k) sA[k] = e[k] * inv;
  }
  __syncthreads();

  if (tid < 8) alphas[b * 8 + tid] = sA[tid];
  if (tid < 128) {                                  // agg_b = alphas @ kernels_bias
    float acc = 0.0f;
    #pragma unroll
    for (int k = 0; k < 8; ++k) acc = fmaf(sA[k], kbias[k * 128 + tid], acc);
    aggb[b * 128 + tid] = acc;
  }
}

// ---------------- Kernel 3: aggregate conv weights -> bf16 -------------------
// grid = (co=128, bgroup=4), 128 threads (ci). out layout [b][tap][co][ci].
__global__ __launch_bounds__(128) void agg_weights_kernel(
    const float* __restrict__ kw, const float* __restrict__ alphas,
    __hip_bfloat16* __restrict__ aggw) {
  const int co = blockIdx.x;
  const int bg = blockIdx.y;
  const int ci = threadIdx.x;
  __shared__ float sA[64];                          // [bb][k]
  if (ci < 64) sA[ci] = alphas[bg * 64 + ci];
  __syncthreads();

  float acc[8][9];
  #pragma unroll
  for (int bb = 0; bb < 8; ++bb)
    #pragma unroll
    for (int t = 0; t < 9; ++t) acc[bb][t] = 0.0f;

  for (int k = 0; k < 8; ++k) {
    const float* src = kw + (((size_t)(k * 128 + co)) * 128 + ci) * 9;
    float w9[9];
    #pragma unroll
    for (int t = 0; t < 9; ++t) w9[t] = src[t];
    #pragma unroll
    for (int bb = 0; bb < 8; ++bb) {
      float a = sA[bb * 8 + k];
      #pragma unroll
      for (int t = 0; t < 9; ++t) acc[bb][t] = fmaf(a, w9[t], acc[bb][t]);
    }
  }
  #pragma unroll
  for (int bb = 0; bb < 8; ++bb)
    #pragma unroll
    for (int t = 0; t < 9; ++t)
      aggw[((((size_t)(bg * 8 + bb) * 9 + t) * 128 + co) << 7) + ci] =
          __float2bfloat16(acc[bb][t]);
}

// ---------------- Kernel 4: per-sample conv as implicit GEMM -----------------
// Block tile: M=128 (co) x N=128 (2 rows x 64 cols). 4 waves, 64x64 each.
// K-loop: 9 taps x 4 ci-chunks of 32 (BK=32), 16x16x32 bf16 MFMA.
// x staged per ci-half (64 ci) in LDS NHWC with 16B XOR swizzle; A double-buffered.
#define XTILE_B 33792   // 264 positions * 128B (64 ci bf16)
#define ATILE_B 8192    // 128 co * 64B (32 ci bf16)

__global__ __launch_bounds__(256) void dyn_conv_kernel(
    const __hip_bfloat16* __restrict__ xT, const __hip_bfloat16* __restrict__ aggw,
    const float* __restrict__ aggb, float* __restrict__ out) {
  const int tile = blockIdx.x;   // 0..31 -> rows [2*tile, 2*tile+1]
  const int b    = blockIdx.y;   // sample
  const int tid  = threadIdx.x;
  const int wv = tid >> 6, lane = tid & 63;
  const int wm = wv >> 1, wn = wv & 1;
  const int lm = lane & 15, quad = lane >> 4;
  const int r0 = tile * 2;

  __shared__ __align__(16) char smem[XTILE_B + 2 * ATILE_B + 512];
  char* xb = smem;
  char* abuf = smem + XTILE_B;
  float* sBias = (float*)(smem + XTILE_B + 2 * ATILE_B);

  if (tid < 128) sBias[tid] = aggb[b * 128 + tid];

  // zero-fill halo slots that staging never writes (pad cols / out-of-range rows)
  for (int pos = tid; pos < 264; pos += 256) {
    int tr = pos / 66, tc = pos - tr * 66;
    int h = r0 - 1 + tr, w = tc - 1;
    if ((unsigned)h >= 64u || (unsigned)w >= 64u) {
      int4* d = (int4*)(xb + pos * 128);
      #pragma unroll
      for (int i = 0; i < 8; ++i) d[i] = make_int4(0, 0, 0, 0);
    }
  }

  const char* xTb = (const char*)xT + ((size_t)b << 20);     // b*4096*256
  const char* awb = (const char*)aggw + (size_t)b * 294912;  // b*9*128*256

  auto stageX = [&](int half) {
    for (int i = wv; i < 33; i += 4) {          // 33 issues of 64x16B = 1KB
      int P = (i << 6) + lane;
      int pos = P >> 3, slot = P & 7;
      int tr = pos / 66, tc = pos - tr * 66;
      int h = r0 - 1 + tr, w = tc - 1;
      char* dst = xb + (i << 10);               // wave-uniform LDS base
      if ((unsigned)h < 64u && (unsigned)w < 64u) {
        int p = slot ^ (pos & 7);               // swizzled source piece
        const char* src = xTb + (((h << 6) + w) << 8) + (half << 7) + (p << 4);
        g2l16(src, dst);
      }
    }
  };
  auto stageA = [&](int c) {                    // chunk c -> buffer c&1
    int tap = (c % 18) >> 1;
    int cic = ((c / 18) << 1) | (c & 1);        // ci chunk 0..3
    char* ab = abuf + (c & 1) * ATILE_B;
    const char* base = awb + (tap << 15);
    #pragma unroll
    for (int jj = 0; jj < 2; ++jj) {
      int j = wv * 2 + jj;
      int co = (j << 4) + (lane >> 2);
      int f = lane & 3;
      int p = f ^ ((co >> 1) & 3);              // swizzled source piece
      const char* src = base + (co << 8) + (cic << 6) + (p << 4);
      g2l16(src, ab + (j << 10));
    }
  };

  int posb[4];
  #pragma unroll
  for (int ni = 0; ni < 4; ++ni) {
    int n = wn * 64 + ni * 16 + lm;
    posb[ni] = (n >> 6) * 66 + (n & 63);
  }
  const int fA = (quad ^ ((lm >> 1) & 3)) << 4;
  int aoff[4];
  #pragma unroll
  for (int mi = 0; mi < 4; ++mi) {
    int co = wm * 64 + mi * 16 + lm;
    aoff[mi] = (co << 6) + fA;
  }

  v4f acc[4][4];
  #pragma unroll
  for (int mi = 0; mi < 4; ++mi)
    #pragma unroll
    for (int ni = 0; ni < 4; ++ni) acc[mi][ni] = v4f{0.f, 0.f, 0.f, 0.f};

  auto computeChunk = [&](int c) {
    int tap = (c % 18) >> 1, sub = c & 1;
    int th = tap / 3, tw = tap - th * 3;
    char* ab = abuf + (c & 1) * ATILE_B;
    v8bf af[4], bfr[4];
    #pragma unroll
    for (int mi = 0; mi < 4; ++mi) af[mi] = *(const v8bf*)(ab + aoff[mi]);
    const int piece = (sub << 2) | quad;        // ci piece within half
    #pragma unroll
    for (int ni = 0; ni < 4; ++ni) {
      int pos = posb[ni] + th * 66 + tw;
      int pp = (piece ^ (pos & 7)) << 4;
      bfr[ni] = *(const v8bf*)(xb + (pos << 7) + pp);
    }
    #pragma unroll
    for (int mi = 0; mi < 4; ++mi)
      #pragma unroll
      for (int ni = 0; ni < 4; ++ni)
        acc[mi][ni] = __builtin_amdgcn_mfma_f32_16x16x32_bf16(
            af[mi], bfr[ni], acc[mi][ni], 0, 0, 0);
  };

  // ---- main loop: x half 0 (chunks 0..17), then half 1 (18..35) ----
  stageX(0);
  stageA(0);
  __syncthreads();
  for (int c = 0; c < 18; ++c) {
    if (c < 17) stageA(c + 1);
    computeChunk(c);
    __syncthreads();
  }
  stageX(1);
  stageA(18);
  __syncthreads();
  for (int c = 18; c < 36; ++c) {
    if (c < 35) stageA(c + 1);
    computeChunk(c);
    __syncthreads();
  }

  // ---- epilogue: C/D layout col=lane&15, row=quad*4+reg ----
  #pragma unroll
  for (int mi = 0; mi < 4; ++mi) {
    #pragma unroll
    for (int r = 0; r < 4; ++r) {
      int co = wm * 64 + mi * 16 + quad * 4 + r;
      float bias = sBias[co];
      #pragma unroll
      for (int ni = 0; ni < 4; ++ni) {
        int n = wn * 64 + ni * 16 + lm;
        out[(((size_t)(b * 128 + co)) << 12) + tile * 128 + n] =
            acc[mi][ni][r] + bias;
      }
    }
  }
}

// ---------------------------------- launch -----------------------------------
extern "C" void kernel_launch(void* const* d_in, const int* in_sizes, int n_in,
                              void* d_out, int out_size, void* d_ws, size_t ws_size,
                              hipStream_t stream) {
  const float* x      = (const float*)d_in[0];
  const float* prompt = (const float*)d_in[1];
  const float* w1     = (const float*)d_in[2];
  const float* b1     = (const float*)d_in[3];
  const float* w2     = (const float*)d_in[4];
  const float* b2     = (const float*)d_in[5];
  const float* kw     = (const float*)d_in[6];
  const float* kb     = (const float*)d_in[7];
  float* out = (float*)d_out;
  char* ws = (char*)d_ws;

  __hip_bfloat16* xT   = (__hip_bfloat16*)(ws + XT_OFF);
  __hip_bfloat16* aggw = (__hip_bfloat16*)(ws + AGGW_OFF);
  float* pooled = (float*)(ws + POOL_OFF);
  float* alphas = (float*)(ws + ALPHA_OFF);
  float* aggb   = (float*)(ws + AGGB_OFF);

  hipMemsetAsync(pooled, 0, POOL_BYTES, stream);
  pool_convert_kernel<<<2048, 256, 0, stream>>>(x, pooled, xT);
  attn_mlp_kernel<<<32, 256, 0, stream>>>(pooled, w1, b1, w2, b2, prompt, kb,
                                          alphas, aggb);
  agg_weights_kernel<<<dim3(128, 4), 128, 0, stream>>>(kw, alphas, aggw);
  dyn_conv_kernel<<<dim3(32, 32), 256, 0, stream>>>(xT, aggw, aggb, out);
}